// Round 9
// baseline (1931.889 us; speedup 1.0000x reference)
//
#include <hip/hip_runtime.h>
#include <hip/hip_bf16.h>
#include <math.h>

typedef short bf16x8 __attribute__((ext_vector_type(8)));
typedef float f32x4 __attribute__((ext_vector_type(4)));
typedef unsigned int u32;
typedef unsigned short u16;

#define NROWS 131072
#define DDIM 224
#define HREAL 400
#define HP 416          // padded hidden dim (13*32)
#define ROWS 32         // rows per block
#define PROW 832        // bytes per plane row (416 * 2B = 52 units of 16B)
#define LDS_TOTAL 26624 // single bf16 activation plane [32][416]; 6 blocks/CU

// ---- workspace layout (bytes); weights interleaved hi|lo per fragment ----
#define OFF_W1    0          // [26nb][7ks][4g][16l][8hi|8lo] u16 = 372736 B
#define OFF_W2    372736     // [26][13][4][16][16] = 692224 B
#define OFF_W5    1064960    // 692224 B
#define OFF_W6    1757184    // [14][13][4][16][16] = 372736 B
#define OFF_C     2129920    // f32 scalar ||d||
#define OFF_MSEP  2129936    // f32 [4096]
#define OFF_DEFEN 2146320    // f32 [131072]
#define OFF_CAND  2670608    // f32 [1280]
// total 2675728 bytes

__device__ __forceinline__ u16 f2bf(float v) {
  union { float f; u32 u; } a; a.f = v;
  u32 u = a.u;
  u += 0x7fffu + ((u >> 16) & 1u);   // round-to-nearest-even
  return (u16)(u >> 16);
}
__device__ __forceinline__ float bf2f(u16 h) {
  union { u32 u; float f; } a; a.u = ((u32)h) << 16; return a.f;
}
// rotation swizzle: 16B unit u of row r lives at unit (u+r) mod 52.
// bijective for ANY row stride; consecutive rows hit distinct bank groups.
__device__ __forceinline__ int rotu(int r, int u) {
  int s = u + r;
  if (s >= 52) s -= 52;
  if (s >= 52) s -= 52;   // r<=31, u<=51 -> s<=82
  return s;
}

// interleaved fragment packing: u16 index i -> (nb, ks, g, l15, half, e)
__device__ __forceinline__ void pack16(int i, int NKS, int KREAL, int NREAL, int NLD,
                                       const float* __restrict__ W,
                                       u16* __restrict__ Wo) {
  const int e = i & 7, half = (i >> 3) & 1;
  const int l15 = (i >> 4) & 15, g = (i >> 8) & 3;
  const int rest = i >> 10;
  const int ks = rest % NKS, nb = rest / NKS;
  const int n = nb * 16 + l15, k = ks * 32 + g * 8 + e;
  const float w = (n < NREAL && k < KREAL) ? W[k * NLD + n] : 0.f;
  const u16 h = f2bf(w);
  Wo[i] = half ? f2bf(w - bf2f(h)) : h;
}

__global__ void k_prep(const float* __restrict__ We1, const float* __restrict__ We2,
                       const float* __restrict__ Wd2, const float* __restrict__ Wd3,
                       const float* __restrict__ dvec,
                       u16* __restrict__ W1, u16* __restrict__ W2,
                       u16* __restrict__ W5, u16* __restrict__ W6,
                       float* __restrict__ Cout) {
  const int t = blockIdx.x * 256 + threadIdx.x;
  const int NT = gridDim.x * 256;
  for (int i = t; i < 26 * 7 * 1024;  i += NT) pack16(i, 7,  DDIM,  HREAL, HREAL, We1, W1);
  for (int i = t; i < 26 * 13 * 1024; i += NT) pack16(i, 13, HREAL, HREAL, HREAL, We2, W2);
  for (int i = t; i < 26 * 13 * 1024; i += NT) pack16(i, 13, HREAL, HREAL, HREAL, Wd2, W5);
  for (int i = t; i < 14 * 13 * 1024; i += NT) pack16(i, 13, HREAL, DDIM,  DDIM,  Wd3, W6);
  if (blockIdx.x == 0) {
    float s = 0.f;
    for (int i = threadIdx.x; i < DDIM; i += 256) { float v = dvec[i]; s += v * v; }
#pragma unroll
    for (int off = 1; off < 64; off <<= 1) s += __shfl_xor(s, off);
    __shared__ float cs[4];
    if ((threadIdx.x & 63) == 0) cs[threadIdx.x >> 6] = s;
    __syncthreads();
    if (threadIdx.x == 0) Cout[0] = sqrtf(cs[0] + cs[1] + cs[2] + cs[3]);
  }
}

// ---------------- GEMM core: one wave, 2 M-frags x NFW N-frags ----------------
// A (activations) bf16 from LDS; W split hi+lo (2 MFMAs per tile).
template <int NKS, int NFW>
__device__ __forceinline__ void gemm_acc(const char* hp,
    const u16* __restrict__ W, int nb0, int l15, int g, f32x4 (&acc)[2][7]) {
  const int lof = (g << 8) + (l15 << 4);
#pragma unroll 2
  for (int ks = 0; ks < NKS; ++ks) {
    int s0 = ks * 4 + g + l15;
    if (s0 >= 52) s0 -= 52;          // <= 66 pre-sub
    int s1 = s0 + 16;
    if (s1 >= 52) s1 -= 52;
    const bf16x8 a0 = *(const bf16x8*)(hp + l15 * PROW + s0 * 16);
    const bf16x8 a1 = *(const bf16x8*)(hp + (l15 + 16) * PROW + s1 * 16);
#pragma unroll
    for (int nf = 0; nf < NFW; ++nf) {
      const u16* base = W + ((((size_t)(nb0 + nf) * NKS + ks) << 10) + lof);
      const bf16x8 bh = *(const bf16x8*)base;
      const bf16x8 bl = *(const bf16x8*)(base + 8);
      acc[0][nf] = __builtin_amdgcn_mfma_f32_16x16x32_bf16(a0, bh, acc[0][nf], 0, 0, 0);
      acc[0][nf] = __builtin_amdgcn_mfma_f32_16x16x32_bf16(a0, bl, acc[0][nf], 0, 0, 0);
      acc[1][nf] = __builtin_amdgcn_mfma_f32_16x16x32_bf16(a1, bh, acc[1][nf], 0, 0, 0);
      acc[1][nf] = __builtin_amdgcn_mfma_f32_16x16x32_bf16(a1, bl, acc[1][nf], 0, 0, 0);
    }
  }
}

// ---------------- activation epilogue: bias + lrelu -> plane ----------------
template <int NFW>
__device__ __forceinline__ void epi_act(f32x4 (&acc)[2][7], const float* __restrict__ bias,
                                        int nb0, char* hp, int l15, int g) {
#pragma unroll
  for (int nf = 0; nf < NFW; ++nf) {
    const int col = (nb0 + nf) * 16 + l15;
    const float bv = (col < HREAL) ? bias[col] : 0.f;
    const int cu = col >> 3;            // 16B unit index
    const int crem = (col & 7) * 2;     // byte within unit
#pragma unroll
    for (int mf = 0; mf < 2; ++mf) {
#pragma unroll
      for (int j = 0; j < 4; ++j) {
        const int row = mf * 16 + g * 4 + j;
        float v = acc[mf][nf][j] + bv;
        v = fmaxf(v, 0.1f * v);
        *(u16*)(hp + row * PROW + rotu(row, cu) * 16 + crem) = f2bf(v);
      }
    }
  }
}

// ---------------- main fused kernel: 32 rows per block, 256 threads ----------------
__global__ __launch_bounds__(256, 8) void k_main(
    const float* __restrict__ xin, const float* __restrict__ dvec,
    const float* __restrict__ be1, const float* __restrict__ be2, const float* __restrict__ be3,
    const float* __restrict__ bd1, const float* __restrict__ bd2, const float* __restrict__ bd3,
    const float* __restrict__ We3, const float* __restrict__ Wd1,
    const u16* __restrict__ W1, const u16* __restrict__ W2,
    const u16* __restrict__ W5, const u16* __restrict__ W6,
    const float* __restrict__ Cptr,
    float* __restrict__ y_out, float* __restrict__ z_out,
    float* __restrict__ defen, float* __restrict__ msep) {
  extern __shared__ __align__(16) char lds[];
  char* hp = lds;              // [32][416] bf16 activation plane, rotation-swizzled

  const int tid = threadIdx.x;
  const int lane = tid & 63;
  const int wid = tid >> 6;       // 0..3
  const int l15 = lane & 15;
  const int g = lane >> 4;        // 0..3
  const int row0 = blockIdx.x * ROWS;
  // hidden layers: 26 n-blocks over 4 waves -> {7,7,6,6}
  const int nb0_26 = (wid < 2) ? wid * 7 : 14 + (wid - 2) * 6;

  // ---- stage x -> plane (bf16) ----
#pragma unroll
  for (int i = 0; i < 7; ++i) {
    const int f = i * 256 + tid;                 // 32 rows * 56 float4
    const int r = f / 56, c4 = f - r * 56;       // c4: 4-col group (8B in plane)
    const float4 v = *(const float4*)(xin + (size_t)(row0 + r) * DDIM + c4 * 4);
    const float vv[4] = {v.x, v.y, v.z, v.w};
    ushort4 hh;
    u16* hw = (u16*)&hh;
#pragma unroll
    for (int w = 0; w < 4; ++w) hw[w] = f2bf(vv[w]);
    *(ushort4*)(hp + r * PROW + rotu(r, c4 >> 1) * 16 + (c4 & 1) * 8) = hh;
  }
  __syncthreads();

  // ---- L1: x(224) -> h1 ----
  {
    f32x4 acc[2][7] = {};
    if (wid < 2) gemm_acc<7, 7>(hp, W1, nb0_26, l15, g, acc);
    else         gemm_acc<7, 6>(hp, W1, nb0_26, l15, g, acc);
    __syncthreads();
    if (wid < 2) epi_act<7>(acc, be1, nb0_26, hp, l15, g);
    else         epi_act<6>(acc, be1, nb0_26, hp, l15, g);
  }
  __syncthreads();

  // ---- L2: h1 -> h2 ----
  {
    f32x4 acc[2][7] = {};
    if (wid < 2) gemm_acc<13, 7>(hp, W2, nb0_26, l15, g, acc);
    else         gemm_acc<13, 6>(hp, W2, nb0_26, l15, g, acc);
    __syncthreads();
    if (wid < 2) epi_act<7>(acc, be2, nb0_26, hp, l15, g);
    else         epi_act<6>(acc, be2, nb0_26, hp, l15, g);
  }
  __syncthreads();

  // ---- L3: z = h2 @ We3 + be3 (Z=4), f32; z stays in registers ----
  float zval;   // z_{t8&3} for row tid>>3
  {
    const int r = tid >> 3, t8 = tid & 7;
    const int j = t8 & 3, half = t8 >> 2;
    const char* hb = hp + r * PROW;
    float s0 = 0.f, s1 = 0.f;
#pragma unroll 2
    for (int it = 0; it < 25; ++it) {
      const int k = half * 200 + it * 8;
      const bf16x8 h8 = *(const bf16x8*)(hb + rotu(r, k >> 3) * 16);
#pragma unroll
      for (int u = 0; u < 8; ++u) {
        const float h = bf2f((u16)h8[u]);
        if (u & 1) s1 = fmaf(h, We3[(k + u) * 4 + j], s1);
        else       s0 = fmaf(h, We3[(k + u) * 4 + j], s0);
      }
    }
    float s = s0 + s1;
    s += __shfl_xor(s, 4);
    s += be3[j];
    zval = s;
    if (half == 0) z_out[(size_t)(row0 + r) * 4 + j] = s;
  }
  // no barrier: row r is read (L3) and written (L4) only by its own 8-thread
  // group inside one wave; program order serializes them.

  // ---- L4: g1 = lrelu(z @ Wd1 + bd1) -> plane ----
  {
    const int r = tid >> 3, q = tid & 7;
    float z[4];
#pragma unroll
    for (int j = 0; j < 4; ++j) z[j] = __shfl(zval, (lane & ~7) + j);
#pragma unroll 2
    for (int uu = 0; uu < 13; ++uu) {
      const int c4 = q * 13 + uu;                // 104 groups of 4 cols = 416
      ushort4 hh;
      u16* hw = (u16*)&hh;
#pragma unroll
      for (int w = 0; w < 4; ++w) {
        const int c = c4 * 4 + w;
        float v = 0.f;
        if (c < HREAL) {
          v = fmaf(z[0], Wd1[c], fmaf(z[1], Wd1[HREAL + c],
              fmaf(z[2], Wd1[2 * HREAL + c], fmaf(z[3], Wd1[3 * HREAL + c], bd1[c]))));
          v = fmaxf(v, 0.1f * v);
        }
        hw[w] = f2bf(v);
      }
      *(ushort4*)(hp + r * PROW + rotu(r, c4 >> 1) * 16 + (c4 & 1) * 8) = hh;
    }
  }
  __syncthreads();

  // ---- L5: g2 = lrelu(g1 @ Wd2 + bd2) ----
  {
    f32x4 acc[2][7] = {};
    if (wid < 2) gemm_acc<13, 7>(hp, W5, nb0_26, l15, g, acc);
    else         gemm_acc<13, 6>(hp, W5, nb0_26, l15, g, acc);
    __syncthreads();
    if (wid < 2) epi_act<7>(acc, bd2, nb0_26, hp, l15, g);
    else         epi_act<6>(acc, bd2, nb0_26, hp, l15, g);
  }
  __syncthreads();

  // ---- L6: y = tanh(g2 @ Wd3 + bd3) + fused reductions ----
  // 14 n-blocks over 4 waves -> {4,4,3,3}
  {
    const int nb0 = (wid < 2) ? wid * 4 : 8 + (wid - 2) * 3;
    const int nfw = (wid < 2) ? 4 : 3;
    f32x4 acc[2][7] = {};
    if (wid < 2) gemm_acc<13, 4>(hp, W6, nb0, l15, g, acc);
    else         gemm_acc<13, 3>(hp, W6, nb0, l15, g, acc);
    __syncthreads();               // all plane reads done; red overlays plane
    float* red = (float*)lds;      // [32 rows][4 waves][4]
#pragma unroll
    for (int mf = 0; mf < 2; ++mf) {
#pragma unroll
      for (int j = 0; j < 4; ++j) {
        const int lrow = mf * 16 + g * 4 + j;
        const int grow = row0 + lrow;
        float pA = 0.f, pB = 0.f, pM = 0.f;
#pragma unroll
        for (int nf = 0; nf < 4; ++nf) {
          if (nf < nfw) {
            const int col = (nb0 + nf) * 16 + l15;
            const float v = acc[mf][nf][j] + bd3[col];
            const float e = __expf(2.f * v);
            const float y = 1.f - 2.f * __builtin_amdgcn_rcpf(e + 1.f);
            y_out[(size_t)grow * DDIM + col] = y;
            pA = fmaf(y, dvec[col], pA);
            pB = fmaf(y, y, pB);
            const float df = y - xin[(size_t)grow * DDIM + col];
            pM = fmaf(df, df, pM);
          }
        }
#pragma unroll
        for (int off = 1; off < 16; off <<= 1) {
          pA += __shfl_xor(pA, off);
          pB += __shfl_xor(pB, off);
          pM += __shfl_xor(pM, off);
        }
        if (l15 == 0) {
          red[(lrow * 4 + wid) * 4 + 0] = pA;
          red[(lrow * 4 + wid) * 4 + 1] = pB;
          red[(lrow * 4 + wid) * 4 + 2] = pM;
        }
      }
    }
  }
  __syncthreads();

  if (tid < 32) {
    const float Cn = Cptr[0];
    const float* red = (const float*)lds;
    float A = 0.f, B2 = 0.f, M = 0.f;
#pragma unroll
    for (int w = 0; w < 4; ++w) {
      A  += red[(tid * 4 + w) * 4 + 0];
      B2 += red[(tid * 4 + w) * 4 + 1];
      M  += red[(tid * 4 + w) * 4 + 2];
    }
    defen[row0 + tid] = A / (sqrtf(B2) * Cn + 1e-5f);
#pragma unroll
    for (int off = 1; off < 32; off <<= 1) M += __shfl_xor(M, off);
    if (tid == 0) msep[blockIdx.x] = M;
  }
}

// ---------------- top-k stage A: 64 blocks, per-block top-20 of 2048 ----------------
__global__ void k_topk_a(const float* __restrict__ defen, float* __restrict__ cand) {
  __shared__ float vals[2048];
  __shared__ float wv[4];
  __shared__ int wi[4];
  const int tid = threadIdx.x;
  const int base = blockIdx.x * 2048;
  for (int i = tid; i < 2048; i += 256) vals[i] = defen[base + i];
  __syncthreads();
  for (int it = 0; it < 20; ++it) {
    float mv = -1e30f; int mi = 1 << 30;
    for (int i = tid; i < 2048; i += 256) {
      float v = vals[i];
      if (v > mv) { mv = v; mi = i; }
    }
#pragma unroll
    for (int off = 1; off < 64; off <<= 1) {
      float ov = __shfl_xor(mv, off); int oi = __shfl_xor(mi, off);
      if (ov > mv || (ov == mv && oi < mi)) { mv = ov; mi = oi; }
    }
    if ((tid & 63) == 0) { wv[tid >> 6] = mv; wi[tid >> 6] = mi; }
    __syncthreads();
    if (tid == 0) {
      float bv = wv[0]; int bi = wi[0];
      for (int q = 1; q < 4; ++q)
        if (wv[q] > bv || (wv[q] == bv && wi[q] < bi)) { bv = wv[q]; bi = wi[q]; }
      cand[blockIdx.x * 20 + it] = bv;
      vals[bi] = -1e30f;
    }
    __syncthreads();
  }
}

// ---------------- top-k stage B: final top-20 of 1280 + R_loss ----------------
__global__ void k_topk_b(const float* __restrict__ cand, const float* __restrict__ msep,
                         float* __restrict__ rloss) {
  __shared__ float vals[1280];
  __shared__ float wv[4];
  __shared__ int wi[4];
  __shared__ float msum[4];
  const int tid = threadIdx.x;
  for (int i = tid; i < 1280; i += 256) vals[i] = cand[i];
  float ms = 0.f;
  for (int i = tid; i < 4096; i += 256) ms += msep[i];
#pragma unroll
  for (int off = 1; off < 64; off <<= 1) ms += __shfl_xor(ms, off);
  if ((tid & 63) == 0) msum[tid >> 6] = ms;
  __syncthreads();
  float sam = 0.f;
  for (int it = 0; it < 20; ++it) {
    float mv = -1e30f; int mi = 1 << 30;
    for (int i = tid; i < 1280; i += 256) {
      float v = vals[i];
      if (v > mv) { mv = v; mi = i; }
    }
#pragma unroll
    for (int off = 1; off < 64; off <<= 1) {
      float ov = __shfl_xor(mv, off); int oi = __shfl_xor(mi, off);
      if (ov > mv || (ov == mv && oi < mi)) { mv = ov; mi = oi; }
    }
    if ((tid & 63) == 0) { wv[tid >> 6] = mv; wi[tid >> 6] = mi; }
    __syncthreads();
    if (tid == 0) {
      float bv = wv[0]; int bi = wi[0];
      for (int q = 1; q < 4; ++q)
        if (wv[q] > bv || (wv[q] == bv && wi[q] < bi)) { bv = wv[q]; bi = wi[q]; }
      sam += bv;
      vals[bi] = -1e30f;
    }
    __syncthreads();
  }
  if (tid == 0) {
    float mse = (msum[0] + msum[1] + msum[2] + msum[3]) / 29360128.f;  // N*D
    rloss[0] = mse + 0.1f * sam;
  }
}

extern "C" void kernel_launch(void* const* d_in, const int* in_sizes, int n_in,
                              void* d_out, int out_size, void* d_ws, size_t ws_size,
                              hipStream_t stream) {
  const float* x    = (const float*)d_in[0];
  const float* dinp = (const float*)d_in[1];
  const float* We1  = (const float*)d_in[2];
  const float* be1  = (const float*)d_in[3];
  const float* We2  = (const float*)d_in[4];
  const float* be2  = (const float*)d_in[5];
  const float* We3  = (const float*)d_in[6];
  const float* be3  = (const float*)d_in[7];
  const float* Wd1  = (const float*)d_in[8];
  const float* bd1  = (const float*)d_in[9];
  const float* Wd2  = (const float*)d_in[10];
  const float* bd2  = (const float*)d_in[11];
  const float* Wd3  = (const float*)d_in[12];
  const float* bd3  = (const float*)d_in[13];

  float* y_out = (float*)d_out;
  float* z_out = y_out + (size_t)NROWS * DDIM;
  float* r_out = z_out + (size_t)NROWS * 4;

  char* ws = (char*)d_ws;
  u16* W1 = (u16*)(ws + OFF_W1);
  u16* W2 = (u16*)(ws + OFF_W2);
  u16* W5 = (u16*)(ws + OFF_W5);
  u16* W6 = (u16*)(ws + OFF_W6);
  float* Cf    = (float*)(ws + OFF_C);
  float* msep  = (float*)(ws + OFF_MSEP);
  float* defen = (float*)(ws + OFF_DEFEN);
  float* cand  = (float*)(ws + OFF_CAND);

  (void)hipFuncSetAttribute((const void*)k_main, hipFuncAttributeMaxDynamicSharedMemorySize, LDS_TOTAL);

  k_prep<<<dim3(256), dim3(256), 0, stream>>>(We1, We2, Wd2, Wd3, dinp, W1, W2, W5, W6, Cf);
  k_main<<<dim3(4096), dim3(256), LDS_TOTAL, stream>>>(x, dinp, be1, be2, be3, bd1, bd2, bd3,
                                                       We3, Wd1, W1, W2, W5, W6,
                                                       Cf, y_out, z_out, defen, msep);
  k_topk_a<<<dim3(64), dim3(256), 0, stream>>>(defen, cand);
  k_topk_b<<<dim3(1), dim3(256), 0, stream>>>(cand, msep, r_out);
}

// Round 10
// 672.491 us; speedup vs baseline: 2.8727x; 2.8727x over previous
//
#include <hip/hip_runtime.h>
#include <hip/hip_bf16.h>
#include <math.h>

typedef short bf16x8 __attribute__((ext_vector_type(8)));
typedef float f32x4 __attribute__((ext_vector_type(4)));
typedef unsigned int u32;
typedef unsigned short u16;

#define NROWS 131072
#define DDIM 224
#define HREAL 400
#define HP 416          // padded hidden dim (13*32)
#define ROWS 32         // rows per block
#define PROW 832        // bytes per plane row (416 * 2B = 52 units of 16B)
#define LDS_TOTAL 26624 // single bf16 activation plane [32][416]

// ---- workspace layout (bytes); weights interleaved hi|lo per fragment ----
#define OFF_W1    0          // [26nb][7ks][4g][16l][8hi|8lo] u16 = 372736 B
#define OFF_W2    372736     // [26][13][4][16][16] = 692224 B
#define OFF_W5    1064960    // 692224 B
#define OFF_W6    1757184    // [14][13][4][16][16] = 372736 B
#define OFF_C     2129920    // f32 scalar ||d||
#define OFF_MSEP  2129936    // f32 [4096]
#define OFF_DEFEN 2146320    // f32 [131072]
#define OFF_CAND  2670608    // f32 [1280]
// total 2675728 bytes

__device__ __forceinline__ u16 f2bf(float v) {
  union { float f; u32 u; } a; a.f = v;
  u32 u = a.u;
  u += 0x7fffu + ((u >> 16) & 1u);   // round-to-nearest-even
  return (u16)(u >> 16);
}
__device__ __forceinline__ float bf2f(u16 h) {
  union { u32 u; float f; } a; a.u = ((u32)h) << 16; return a.f;
}
// rotation swizzle: 16B unit u of row r lives at unit (u+r) mod 52.
// bijective for ANY row stride; consecutive rows hit distinct bank groups.
__device__ __forceinline__ int rotu(int r, int u) {
  int s = u + r;
  if (s >= 52) s -= 52;
  if (s >= 52) s -= 52;   // r<=31, u<=51 -> s<=82
  return s;
}

// interleaved fragment packing: u16 index i -> (nb, ks, g, l15, half, e)
__device__ __forceinline__ void pack16(int i, int NKS, int KREAL, int NREAL, int NLD,
                                       const float* __restrict__ W,
                                       u16* __restrict__ Wo) {
  const int e = i & 7, half = (i >> 3) & 1;
  const int l15 = (i >> 4) & 15, g = (i >> 8) & 3;
  const int rest = i >> 10;
  const int ks = rest % NKS, nb = rest / NKS;
  const int n = nb * 16 + l15, k = ks * 32 + g * 8 + e;
  const float w = (n < NREAL && k < KREAL) ? W[k * NLD + n] : 0.f;
  const u16 h = f2bf(w);
  Wo[i] = half ? f2bf(w - bf2f(h)) : h;
}

__global__ void k_prep(const float* __restrict__ We1, const float* __restrict__ We2,
                       const float* __restrict__ Wd2, const float* __restrict__ Wd3,
                       const float* __restrict__ dvec,
                       u16* __restrict__ W1, u16* __restrict__ W2,
                       u16* __restrict__ W5, u16* __restrict__ W6,
                       float* __restrict__ Cout) {
  const int t = blockIdx.x * 256 + threadIdx.x;
  const int NT = gridDim.x * 256;
  for (int i = t; i < 26 * 7 * 1024;  i += NT) pack16(i, 7,  DDIM,  HREAL, HREAL, We1, W1);
  for (int i = t; i < 26 * 13 * 1024; i += NT) pack16(i, 13, HREAL, HREAL, HREAL, We2, W2);
  for (int i = t; i < 26 * 13 * 1024; i += NT) pack16(i, 13, HREAL, HREAL, HREAL, Wd2, W5);
  for (int i = t; i < 14 * 13 * 1024; i += NT) pack16(i, 13, HREAL, DDIM,  DDIM,  Wd3, W6);
  if (blockIdx.x == 0) {
    float s = 0.f;
    for (int i = threadIdx.x; i < DDIM; i += 256) { float v = dvec[i]; s += v * v; }
#pragma unroll
    for (int off = 1; off < 64; off <<= 1) s += __shfl_xor(s, off);
    __shared__ float cs[4];
    if ((threadIdx.x & 63) == 0) cs[threadIdx.x >> 6] = s;
    __syncthreads();
    if (threadIdx.x == 0) Cout[0] = sqrtf(cs[0] + cs[1] + cs[2] + cs[3]);
  }
}

// ---------------- GEMM core: one wave, 2 M-frags x NFW N-frags ----------------
// A (activations) bf16 from LDS; W split hi+lo (2 MFMAs per tile).
template <int NKS, int NFW>
__device__ __forceinline__ void gemm_acc(const char* hp,
    const u16* __restrict__ W, int nb0, int l15, int g, f32x4 (&acc)[2][7]) {
  const int lof = (g << 8) + (l15 << 4);
#pragma unroll 2
  for (int ks = 0; ks < NKS; ++ks) {
    int s0 = ks * 4 + g + l15;
    if (s0 >= 52) s0 -= 52;          // <= 66 pre-sub
    int s1 = s0 + 16;
    if (s1 >= 52) s1 -= 52;
    const bf16x8 a0 = *(const bf16x8*)(hp + l15 * PROW + s0 * 16);
    const bf16x8 a1 = *(const bf16x8*)(hp + (l15 + 16) * PROW + s1 * 16);
#pragma unroll
    for (int nf = 0; nf < NFW; ++nf) {
      const u16* base = W + ((((size_t)(nb0 + nf) * NKS + ks) << 10) + lof);
      const bf16x8 bh = *(const bf16x8*)base;
      const bf16x8 bl = *(const bf16x8*)(base + 8);
      acc[0][nf] = __builtin_amdgcn_mfma_f32_16x16x32_bf16(a0, bh, acc[0][nf], 0, 0, 0);
      acc[0][nf] = __builtin_amdgcn_mfma_f32_16x16x32_bf16(a0, bl, acc[0][nf], 0, 0, 0);
      acc[1][nf] = __builtin_amdgcn_mfma_f32_16x16x32_bf16(a1, bh, acc[1][nf], 0, 0, 0);
      acc[1][nf] = __builtin_amdgcn_mfma_f32_16x16x32_bf16(a1, bl, acc[1][nf], 0, 0, 0);
    }
  }
}

// ---------------- activation epilogue: bias + lrelu -> plane ----------------
template <int NFW>
__device__ __forceinline__ void epi_act(f32x4 (&acc)[2][7], const float* __restrict__ bias,
                                        int nb0, char* hp, int l15, int g) {
#pragma unroll
  for (int nf = 0; nf < NFW; ++nf) {
    const int col = (nb0 + nf) * 16 + l15;
    const float bv = (col < HREAL) ? bias[col] : 0.f;
    const int cu = col >> 3;            // 16B unit index
    const int crem = (col & 7) * 2;     // byte within unit
#pragma unroll
    for (int mf = 0; mf < 2; ++mf) {
#pragma unroll
      for (int j = 0; j < 4; ++j) {
        const int row = mf * 16 + g * 4 + j;
        float v = acc[mf][nf][j] + bv;
        v = fmaxf(v, 0.1f * v);
        *(u16*)(hp + row * PROW + rotu(row, cu) * 16 + crem) = f2bf(v);
      }
    }
  }
}

// ---------------- main fused kernel: 32 rows per block, 256 threads ----------------
__global__ __launch_bounds__(256, 4) void k_main(
    const float* __restrict__ xin, const float* __restrict__ dvec,
    const float* __restrict__ be1, const float* __restrict__ be2, const float* __restrict__ be3,
    const float* __restrict__ bd1, const float* __restrict__ bd2, const float* __restrict__ bd3,
    const float* __restrict__ We3, const float* __restrict__ Wd1,
    const u16* __restrict__ W1, const u16* __restrict__ W2,
    const u16* __restrict__ W5, const u16* __restrict__ W6,
    const float* __restrict__ Cptr,
    float* __restrict__ y_out, float* __restrict__ z_out,
    float* __restrict__ defen, float* __restrict__ msep) {
  extern __shared__ __align__(16) char lds[];
  char* hp = lds;              // [32][416] bf16 activation plane, rotation-swizzled

  const int tid = threadIdx.x;
  const int lane = tid & 63;
  const int wid = tid >> 6;       // 0..3
  const int l15 = lane & 15;
  const int g = lane >> 4;        // 0..3
  const int row0 = blockIdx.x * ROWS;
  // hidden layers: 26 n-blocks over 4 waves -> {7,7,6,6}
  const int nb0_26 = (wid < 2) ? wid * 7 : 14 + (wid - 2) * 6;

  // ---- stage x -> plane (bf16) ----
#pragma unroll
  for (int i = 0; i < 7; ++i) {
    const int f = i * 256 + tid;                 // 32 rows * 56 float4
    const int r = f / 56, c4 = f - r * 56;       // c4: 4-col group (8B in plane)
    const float4 v = *(const float4*)(xin + (size_t)(row0 + r) * DDIM + c4 * 4);
    const float vv[4] = {v.x, v.y, v.z, v.w};
    ushort4 hh;
    u16* hw = (u16*)&hh;
#pragma unroll
    for (int w = 0; w < 4; ++w) hw[w] = f2bf(vv[w]);
    *(ushort4*)(hp + r * PROW + rotu(r, c4 >> 1) * 16 + (c4 & 1) * 8) = hh;
  }
  __syncthreads();

  // ---- L1: x(224) -> h1 ----
  {
    f32x4 acc[2][7] = {};
    if (wid < 2) gemm_acc<7, 7>(hp, W1, nb0_26, l15, g, acc);
    else         gemm_acc<7, 6>(hp, W1, nb0_26, l15, g, acc);
    __syncthreads();
    if (wid < 2) epi_act<7>(acc, be1, nb0_26, hp, l15, g);
    else         epi_act<6>(acc, be1, nb0_26, hp, l15, g);
  }
  __syncthreads();

  // ---- L2: h1 -> h2 ----
  {
    f32x4 acc[2][7] = {};
    if (wid < 2) gemm_acc<13, 7>(hp, W2, nb0_26, l15, g, acc);
    else         gemm_acc<13, 6>(hp, W2, nb0_26, l15, g, acc);
    __syncthreads();
    if (wid < 2) epi_act<7>(acc, be2, nb0_26, hp, l15, g);
    else         epi_act<6>(acc, be2, nb0_26, hp, l15, g);
  }
  __syncthreads();

  // ---- L3: z = h2 @ We3 + be3 (Z=4), f32; z stays in registers ----
  float zval;   // z_{t8&3} for row tid>>3
  {
    const int r = tid >> 3, t8 = tid & 7;
    const int j = t8 & 3, half = t8 >> 2;
    const char* hb = hp + r * PROW;
    float s0 = 0.f, s1 = 0.f;
#pragma unroll 2
    for (int it = 0; it < 25; ++it) {
      const int k = half * 200 + it * 8;
      const bf16x8 h8 = *(const bf16x8*)(hb + rotu(r, k >> 3) * 16);
#pragma unroll
      for (int u = 0; u < 8; ++u) {
        const float h = bf2f((u16)h8[u]);
        if (u & 1) s1 = fmaf(h, We3[(k + u) * 4 + j], s1);
        else       s0 = fmaf(h, We3[(k + u) * 4 + j], s0);
      }
    }
    float s = s0 + s1;
    s += __shfl_xor(s, 4);
    s += be3[j];
    zval = s;
    if (half == 0) z_out[(size_t)(row0 + r) * 4 + j] = s;
  }
  // no barrier: row r is read (L3) and written (L4) only by its own 8-thread
  // group inside one wave; program order serializes them.

  // ---- L4: g1 = lrelu(z @ Wd1 + bd1) -> plane ----
  {
    const int r = tid >> 3, q = tid & 7;
    float z[4];
#pragma unroll
    for (int j = 0; j < 4; ++j) z[j] = __shfl(zval, (lane & ~7) + j);
#pragma unroll 2
    for (int uu = 0; uu < 13; ++uu) {
      const int c4 = q * 13 + uu;                // 104 groups of 4 cols = 416
      ushort4 hh;
      u16* hw = (u16*)&hh;
#pragma unroll
      for (int w = 0; w < 4; ++w) {
        const int c = c4 * 4 + w;
        float v = 0.f;
        if (c < HREAL) {
          v = fmaf(z[0], Wd1[c], fmaf(z[1], Wd1[HREAL + c],
              fmaf(z[2], Wd1[2 * HREAL + c], fmaf(z[3], Wd1[3 * HREAL + c], bd1[c]))));
          v = fmaxf(v, 0.1f * v);
        }
        hw[w] = f2bf(v);
      }
      *(ushort4*)(hp + r * PROW + rotu(r, c4 >> 1) * 16 + (c4 & 1) * 8) = hh;
    }
  }
  __syncthreads();

  // ---- L5: g2 = lrelu(g1 @ Wd2 + bd2) ----
  {
    f32x4 acc[2][7] = {};
    if (wid < 2) gemm_acc<13, 7>(hp, W5, nb0_26, l15, g, acc);
    else         gemm_acc<13, 6>(hp, W5, nb0_26, l15, g, acc);
    __syncthreads();
    if (wid < 2) epi_act<7>(acc, bd2, nb0_26, hp, l15, g);
    else         epi_act<6>(acc, bd2, nb0_26, hp, l15, g);
  }
  __syncthreads();

  // ---- L6: y = tanh(g2 @ Wd3 + bd3) + fused reductions ----
  // 14 n-blocks over 4 waves -> {4,4,3,3}
  {
    const int nb0 = (wid < 2) ? wid * 4 : 8 + (wid - 2) * 3;
    const int nfw = (wid < 2) ? 4 : 3;
    f32x4 acc[2][7] = {};
    if (wid < 2) gemm_acc<13, 4>(hp, W6, nb0, l15, g, acc);
    else         gemm_acc<13, 3>(hp, W6, nb0, l15, g, acc);
    __syncthreads();               // all plane reads done; red overlays plane
    float* red = (float*)lds;      // [32 rows][4 waves][4]
#pragma unroll
    for (int mf = 0; mf < 2; ++mf) {
#pragma unroll
      for (int j = 0; j < 4; ++j) {
        const int lrow = mf * 16 + g * 4 + j;
        const int grow = row0 + lrow;
        float pA = 0.f, pB = 0.f, pM = 0.f;
#pragma unroll
        for (int nf = 0; nf < 4; ++nf) {
          if (nf < nfw) {
            const int col = (nb0 + nf) * 16 + l15;
            const float v = acc[mf][nf][j] + bd3[col];
            const float e = __expf(2.f * v);
            const float y = 1.f - 2.f * __builtin_amdgcn_rcpf(e + 1.f);
            y_out[(size_t)grow * DDIM + col] = y;
            pA = fmaf(y, dvec[col], pA);
            pB = fmaf(y, y, pB);
            const float df = y - xin[(size_t)grow * DDIM + col];
            pM = fmaf(df, df, pM);
          }
        }
#pragma unroll
        for (int off = 1; off < 16; off <<= 1) {
          pA += __shfl_xor(pA, off);
          pB += __shfl_xor(pB, off);
          pM += __shfl_xor(pM, off);
        }
        if (l15 == 0) {
          red[(lrow * 4 + wid) * 4 + 0] = pA;
          red[(lrow * 4 + wid) * 4 + 1] = pB;
          red[(lrow * 4 + wid) * 4 + 2] = pM;
        }
      }
    }
  }
  __syncthreads();

  if (tid < 32) {
    const float Cn = Cptr[0];
    const float* red = (const float*)lds;
    float A = 0.f, B2 = 0.f, M = 0.f;
#pragma unroll
    for (int w = 0; w < 4; ++w) {
      A  += red[(tid * 4 + w) * 4 + 0];
      B2 += red[(tid * 4 + w) * 4 + 1];
      M  += red[(tid * 4 + w) * 4 + 2];
    }
    defen[row0 + tid] = A / (sqrtf(B2) * Cn + 1e-5f);
#pragma unroll
    for (int off = 1; off < 32; off <<= 1) M += __shfl_xor(M, off);
    if (tid == 0) msep[blockIdx.x] = M;
  }
}

// ---------------- top-k stage A: 64 blocks, per-block top-20 of 2048 ----------------
__global__ void k_topk_a(const float* __restrict__ defen, float* __restrict__ cand) {
  __shared__ float vals[2048];
  __shared__ float wv[4];
  __shared__ int wi[4];
  const int tid = threadIdx.x;
  const int base = blockIdx.x * 2048;
  for (int i = tid; i < 2048; i += 256) vals[i] = defen[base + i];
  __syncthreads();
  for (int it = 0; it < 20; ++it) {
    float mv = -1e30f; int mi = 1 << 30;
    for (int i = tid; i < 2048; i += 256) {
      float v = vals[i];
      if (v > mv) { mv = v; mi = i; }
    }
#pragma unroll
    for (int off = 1; off < 64; off <<= 1) {
      float ov = __shfl_xor(mv, off); int oi = __shfl_xor(mi, off);
      if (ov > mv || (ov == mv && oi < mi)) { mv = ov; mi = oi; }
    }
    if ((tid & 63) == 0) { wv[tid >> 6] = mv; wi[tid >> 6] = mi; }
    __syncthreads();
    if (tid == 0) {
      float bv = wv[0]; int bi = wi[0];
      for (int q = 1; q < 4; ++q)
        if (wv[q] > bv || (wv[q] == bv && wi[q] < bi)) { bv = wv[q]; bi = wi[q]; }
      cand[blockIdx.x * 20 + it] = bv;
      vals[bi] = -1e30f;
    }
    __syncthreads();
  }
}

// ---------------- top-k stage B: final top-20 of 1280 + R_loss ----------------
__global__ void k_topk_b(const float* __restrict__ cand, const float* __restrict__ msep,
                         float* __restrict__ rloss) {
  __shared__ float vals[1280];
  __shared__ float wv[4];
  __shared__ int wi[4];
  __shared__ float msum[4];
  const int tid = threadIdx.x;
  for (int i = tid; i < 1280; i += 256) vals[i] = cand[i];
  float ms = 0.f;
  for (int i = tid; i < 4096; i += 256) ms += msep[i];
#pragma unroll
  for (int off = 1; off < 64; off <<= 1) ms += __shfl_xor(ms, off);
  if ((tid & 63) == 0) msum[tid >> 6] = ms;
  __syncthreads();
  float sam = 0.f;
  for (int it = 0; it < 20; ++it) {
    float mv = -1e30f; int mi = 1 << 30;
    for (int i = tid; i < 1280; i += 256) {
      float v = vals[i];
      if (v > mv) { mv = v; mi = i; }
    }
#pragma unroll
    for (int off = 1; off < 64; off <<= 1) {
      float ov = __shfl_xor(mv, off); int oi = __shfl_xor(mi, off);
      if (ov > mv || (ov == mv && oi < mi)) { mv = ov; mi = oi; }
    }
    if ((tid & 63) == 0) { wv[tid >> 6] = mv; wi[tid >> 6] = mi; }
    __syncthreads();
    if (tid == 0) {
      float bv = wv[0]; int bi = wi[0];
      for (int q = 1; q < 4; ++q)
        if (wv[q] > bv || (wv[q] == bv && wi[q] < bi)) { bv = wv[q]; bi = wi[q]; }
      sam += bv;
      vals[bi] = -1e30f;
    }
    __syncthreads();
  }
  if (tid == 0) {
    float mse = (msum[0] + msum[1] + msum[2] + msum[3]) / 29360128.f;  // N*D
    rloss[0] = mse + 0.1f * sam;
  }
}

extern "C" void kernel_launch(void* const* d_in, const int* in_sizes, int n_in,
                              void* d_out, int out_size, void* d_ws, size_t ws_size,
                              hipStream_t stream) {
  const float* x    = (const float*)d_in[0];
  const float* dinp = (const float*)d_in[1];
  const float* We1  = (const float*)d_in[2];
  const float* be1  = (const float*)d_in[3];
  const float* We2  = (const float*)d_in[4];
  const float* be2  = (const float*)d_in[5];
  const float* We3  = (const float*)d_in[6];
  const float* be3  = (const float*)d_in[7];
  const float* Wd1  = (const float*)d_in[8];
  const float* bd1  = (const float*)d_in[9];
  const float* Wd2  = (const float*)d_in[10];
  const float* bd2  = (const float*)d_in[11];
  const float* Wd3  = (const float*)d_in[12];
  const float* bd3  = (const float*)d_in[13];

  float* y_out = (float*)d_out;
  float* z_out = y_out + (size_t)NROWS * DDIM;
  float* r_out = z_out + (size_t)NROWS * 4;

  char* ws = (char*)d_ws;
  u16* W1 = (u16*)(ws + OFF_W1);
  u16* W2 = (u16*)(ws + OFF_W2);
  u16* W5 = (u16*)(ws + OFF_W5);
  u16* W6 = (u16*)(ws + OFF_W6);
  float* Cf    = (float*)(ws + OFF_C);
  float* msep  = (float*)(ws + OFF_MSEP);
  float* defen = (float*)(ws + OFF_DEFEN);
  float* cand  = (float*)(ws + OFF_CAND);

  (void)hipFuncSetAttribute((const void*)k_main, hipFuncAttributeMaxDynamicSharedMemorySize, LDS_TOTAL);

  k_prep<<<dim3(256), dim3(256), 0, stream>>>(We1, We2, Wd2, Wd3, dinp, W1, W2, W5, W6, Cf);
  k_main<<<dim3(4096), dim3(256), LDS_TOTAL, stream>>>(x, dinp, be1, be2, be3, bd1, bd2, bd3,
                                                       We3, Wd1, W1, W2, W5, W6,
                                                       Cf, y_out, z_out, defen, msep);
  k_topk_a<<<dim3(64), dim3(256), 0, stream>>>(defen, cand);
  k_topk_b<<<dim3(1), dim3(256), 0, stream>>>(cand, msep, r_out);
}

// Round 11
// 585.785 us; speedup vs baseline: 3.2979x; 1.1480x over previous
//
#include <hip/hip_runtime.h>
#include <hip/hip_bf16.h>
#include <math.h>

typedef short bf16x8 __attribute__((ext_vector_type(8)));
typedef float f32x4 __attribute__((ext_vector_type(4)));
typedef unsigned int u32;
typedef unsigned short u16;

#define NROWS 131072
#define DDIM 224
#define HREAL 400
#define HP 416          // padded hidden dim (13*32)
#define ROWS 32         // rows per block
#define PROW 832        // bytes per plane row (416 * 2B = 52 units of 16B)
#define LDS_TOTAL 26624 // single bf16 activation plane [32][416]

// ---- workspace layout (bytes); weights interleaved hi|lo per fragment ----
#define OFF_W1    0          // [26nb][7ks][4g][16l][8hi|8lo] u16 = 372736 B
#define OFF_W2    372736     // [26][13][4][16][16] = 692224 B
#define OFF_W5    1064960    // 692224 B
#define OFF_W6    1757184    // [14][13][4][16][16] = 372736 B
#define OFF_C     2129920    // f32 scalar ||d||
#define OFF_MSEP  2129936    // f32 [4096]
#define OFF_DEFEN 2146320    // f32 [131072]
#define OFF_CAND  2670608    // f32 [1280]
#define OFF_WE3T  2675728    // f32 [4][416] transposed+padded We3
// total 2682384 bytes

__device__ __forceinline__ u16 f2bf(float v) {
  union { float f; u32 u; } a; a.f = v;
  u32 u = a.u;
  u += 0x7fffu + ((u >> 16) & 1u);   // round-to-nearest-even
  return (u16)(u >> 16);
}
__device__ __forceinline__ float bf2f(u16 h) {
  union { u32 u; float f; } a; a.u = ((u32)h) << 16; return a.f;
}
// rotation swizzle: 16B unit u of row r lives at unit (u+r) mod 52.
__device__ __forceinline__ int rotu(int r, int u) {
  int s = u + r;
  if (s >= 52) s -= 52;
  if (s >= 52) s -= 52;   // r<=31, u<=51 -> s<=82
  return s;
}

// interleaved fragment packing: u16 index i -> (nb, ks, g, l15, half, e)
__device__ __forceinline__ void pack16(int i, int NKS, int KREAL, int NREAL, int NLD,
                                       const float* __restrict__ W,
                                       u16* __restrict__ Wo) {
  const int e = i & 7, half = (i >> 3) & 1;
  const int l15 = (i >> 4) & 15, g = (i >> 8) & 3;
  const int rest = i >> 10;
  const int ks = rest % NKS, nb = rest / NKS;
  const int n = nb * 16 + l15, k = ks * 32 + g * 8 + e;
  const float w = (n < NREAL && k < KREAL) ? W[k * NLD + n] : 0.f;
  const u16 h = f2bf(w);
  Wo[i] = half ? f2bf(w - bf2f(h)) : h;
}

__global__ void k_prep(const float* __restrict__ We1, const float* __restrict__ We2,
                       const float* __restrict__ Wd2, const float* __restrict__ Wd3,
                       const float* __restrict__ We3, const float* __restrict__ dvec,
                       u16* __restrict__ W1, u16* __restrict__ W2,
                       u16* __restrict__ W5, u16* __restrict__ W6,
                       float* __restrict__ We3T, float* __restrict__ Cout) {
  const int t = blockIdx.x * 256 + threadIdx.x;
  const int NT = gridDim.x * 256;
  for (int i = t; i < 26 * 7 * 1024;  i += NT) pack16(i, 7,  DDIM,  HREAL, HREAL, We1, W1);
  for (int i = t; i < 26 * 13 * 1024; i += NT) pack16(i, 13, HREAL, HREAL, HREAL, We2, W2);
  for (int i = t; i < 26 * 13 * 1024; i += NT) pack16(i, 13, HREAL, HREAL, HREAL, Wd2, W5);
  for (int i = t; i < 14 * 13 * 1024; i += NT) pack16(i, 13, HREAL, DDIM,  DDIM,  Wd3, W6);
  for (int i = t; i < 4 * 416; i += NT) {      // We3T[j][k] = We3[k][j], zero-padded
    const int j = i / 416, k = i - j * 416;
    We3T[i] = (k < HREAL) ? We3[k * 4 + j] : 0.f;
  }
  if (blockIdx.x == 0) {
    float s = 0.f;
    for (int i = threadIdx.x; i < DDIM; i += 256) { float v = dvec[i]; s += v * v; }
#pragma unroll
    for (int off = 1; off < 64; off <<= 1) s += __shfl_xor(s, off);
    __shared__ float cs[4];
    if ((threadIdx.x & 63) == 0) cs[threadIdx.x >> 6] = s;
    __syncthreads();
    if (threadIdx.x == 0) Cout[0] = sqrtf(cs[0] + cs[1] + cs[2] + cs[3]);
  }
}

// ---------------- GEMM core: one wave, 2 M-frags x NFW N-frags ----------------
// A bf16 from LDS; W split hi+lo (2 MFMAs/tile); weights double-buffered 1 k-step deep.
template <int NKS, int NFW>
__device__ __forceinline__ void gemm_acc(const char* hp,
    const u16* __restrict__ W, int nb0, int l15, int g, f32x4 (&acc)[2][4]) {
  const int lof = (g << 8) + (l15 << 4);
  const u16* wp[NFW];
#pragma unroll
  for (int nf = 0; nf < NFW; ++nf)
    wp[nf] = W + ((((size_t)(nb0 + nf) * NKS) << 10) + lof);
  bf16x8 cwh[NFW], cwl[NFW];
#pragma unroll
  for (int nf = 0; nf < NFW; ++nf) {
    cwh[nf] = *(const bf16x8*)wp[nf];
    cwl[nf] = *(const bf16x8*)(wp[nf] + 8);
  }
#pragma unroll
  for (int ks = 0; ks < NKS; ++ks) {
    int s0 = ks * 4 + g + l15;
    if (s0 >= 52) s0 -= 52;
    int s1 = s0 + 16;
    if (s1 >= 52) s1 -= 52;
    const bf16x8 a0 = *(const bf16x8*)(hp + l15 * PROW + s0 * 16);
    const bf16x8 a1 = *(const bf16x8*)(hp + (l15 + 16) * PROW + s1 * 16);
    bf16x8 nwh[NFW], nwl[NFW];
    if (ks + 1 < NKS) {
#pragma unroll
      for (int nf = 0; nf < NFW; ++nf) {
        const u16* p = wp[nf] + (size_t)(ks + 1) * 1024;
        nwh[nf] = *(const bf16x8*)p;
        nwl[nf] = *(const bf16x8*)(p + 8);
      }
    }
    __builtin_amdgcn_s_setprio(1);
#pragma unroll
    for (int nf = 0; nf < NFW; ++nf) {
      acc[0][nf] = __builtin_amdgcn_mfma_f32_16x16x32_bf16(a0, cwh[nf], acc[0][nf], 0, 0, 0);
      acc[0][nf] = __builtin_amdgcn_mfma_f32_16x16x32_bf16(a0, cwl[nf], acc[0][nf], 0, 0, 0);
      acc[1][nf] = __builtin_amdgcn_mfma_f32_16x16x32_bf16(a1, cwh[nf], acc[1][nf], 0, 0, 0);
      acc[1][nf] = __builtin_amdgcn_mfma_f32_16x16x32_bf16(a1, cwl[nf], acc[1][nf], 0, 0, 0);
    }
    __builtin_amdgcn_s_setprio(0);
    if (ks + 1 < NKS) {
#pragma unroll
      for (int nf = 0; nf < NFW; ++nf) { cwh[nf] = nwh[nf]; cwl[nf] = nwl[nf]; }
    }
  }
}

// ---------------- activation epilogue: bias + lrelu -> plane ----------------
template <int NFW>
__device__ __forceinline__ void epi_act(f32x4 (&acc)[2][4], const float* __restrict__ bias,
                                        int nb0, char* hp, int l15, int g) {
#pragma unroll
  for (int nf = 0; nf < NFW; ++nf) {
    const int col = (nb0 + nf) * 16 + l15;
    const float bv = (col < HREAL) ? bias[col] : 0.f;
    const int cu = col >> 3;            // 16B unit index
    const int crem = (col & 7) * 2;     // byte within unit
#pragma unroll
    for (int mf = 0; mf < 2; ++mf) {
#pragma unroll
      for (int j = 0; j < 4; ++j) {
        const int row = mf * 16 + g * 4 + j;
        float v = acc[mf][nf][j] + bv;
        v = fmaxf(v, 0.1f * v);
        *(u16*)(hp + row * PROW + rotu(row, cu) * 16 + crem) = f2bf(v);
      }
    }
  }
}

// ---------------- main fused kernel: 32 rows per block, 512 threads ----------------
__global__ __launch_bounds__(512, 4) void k_main(
    const float* __restrict__ xin, const float* __restrict__ dvec,
    const float* __restrict__ be1, const float* __restrict__ be2, const float* __restrict__ be3,
    const float* __restrict__ bd1, const float* __restrict__ bd2, const float* __restrict__ bd3,
    const float* __restrict__ We3T, const float* __restrict__ Wd1,
    const u16* __restrict__ W1, const u16* __restrict__ W2,
    const u16* __restrict__ W5, const u16* __restrict__ W6,
    const float* __restrict__ Cptr,
    float* __restrict__ y_out, float* __restrict__ z_out,
    float* __restrict__ defen, float* __restrict__ msep) {
  extern __shared__ __align__(16) char lds[];
  char* hp = lds;              // [32][416] bf16 activation plane, rotation-swizzled

  const int tid = threadIdx.x;
  const int lane = tid & 63;
  const int wid = tid >> 6;       // 0..7
  const int l15 = lane & 15;
  const int g = lane >> 4;        // 0..3
  const int row0 = blockIdx.x * ROWS;
  // hidden layers: 26 n-blocks over 8 waves -> {4,4,3,3,3,3,3,3}
  const int nb0_26 = (wid < 2) ? wid * 4 : 8 + (wid - 2) * 3;

  // ---- stage x -> plane (bf16) ----
#pragma unroll
  for (int i = 0; i < 4; ++i) {
    const int f = i * 512 + tid;                 // 32 rows * 56 float4 = 1792
    if (f < 1792) {
      const int r = f / 56, c4 = f - r * 56;
      const float4 v = *(const float4*)(xin + (size_t)(row0 + r) * DDIM + c4 * 4);
      const float vv[4] = {v.x, v.y, v.z, v.w};
      ushort4 hh;
      u16* hw = (u16*)&hh;
#pragma unroll
      for (int w = 0; w < 4; ++w) hw[w] = f2bf(vv[w]);
      *(ushort4*)(hp + r * PROW + rotu(r, c4 >> 1) * 16 + (c4 & 1) * 8) = hh;
    }
  }
  __syncthreads();

  // ---- L1: x(224) -> h1 ----
  {
    f32x4 acc[2][4] = {};
    if (wid < 2) gemm_acc<7, 4>(hp, W1, nb0_26, l15, g, acc);
    else         gemm_acc<7, 3>(hp, W1, nb0_26, l15, g, acc);
    __syncthreads();
    if (wid < 2) epi_act<4>(acc, be1, nb0_26, hp, l15, g);
    else         epi_act<3>(acc, be1, nb0_26, hp, l15, g);
  }
  __syncthreads();

  // ---- L2: h1 -> h2 ----
  {
    f32x4 acc[2][4] = {};
    if (wid < 2) gemm_acc<13, 4>(hp, W2, nb0_26, l15, g, acc);
    else         gemm_acc<13, 3>(hp, W2, nb0_26, l15, g, acc);
    __syncthreads();
    if (wid < 2) epi_act<4>(acc, be2, nb0_26, hp, l15, g);
    else         epi_act<3>(acc, be2, nb0_26, hp, l15, g);
  }
  __syncthreads();

  // ---- L3: z = h2 @ We3 + be3 (Z=4), f32; 16 threads/row (j x K-quarter) ----
  float zval;   // finished z_{t16&3} for row tid>>4 (all lanes after reduce)
  {
    const int r = tid >> 4;          // 0..31
    const int t16 = tid & 15;
    const int j = t16 & 3, qk = t16 >> 2;
    const char* hb = hp + r * PROW;
    const float* wrow = We3T + j * 416;
    float s0 = 0.f, s1 = 0.f;
#pragma unroll 2
    for (int it = 0; it < 13; ++it) {
      const int k = qk * 104 + it * 8;
      const bf16x8 h8 = *(const bf16x8*)(hb + rotu(r, qk * 13 + it) * 16);
      const float4 w0 = *(const float4*)(wrow + k);
      const float4 w1 = *(const float4*)(wrow + k + 4);
      s0 = fmaf(bf2f((u16)h8[0]), w0.x, s0);
      s1 = fmaf(bf2f((u16)h8[1]), w0.y, s1);
      s0 = fmaf(bf2f((u16)h8[2]), w0.z, s0);
      s1 = fmaf(bf2f((u16)h8[3]), w0.w, s1);
      s0 = fmaf(bf2f((u16)h8[4]), w1.x, s0);
      s1 = fmaf(bf2f((u16)h8[5]), w1.y, s1);
      s0 = fmaf(bf2f((u16)h8[6]), w1.z, s0);
      s1 = fmaf(bf2f((u16)h8[7]), w1.w, s1);
    }
    float s = s0 + s1;
    s += __shfl_xor(s, 4);
    s += __shfl_xor(s, 8);           // reduce over K-quarters, preserve j
    s += be3[j];
    zval = s;
    if (qk == 0) z_out[(size_t)(row0 + r) * 4 + j] = s;
  }
  // no barrier: row r is read (L3) and written (L4) only by its own 16-thread
  // group inside one wave; program order serializes them.

  // ---- L4: g1 = lrelu(z @ Wd1 + bd1) -> plane ----
  {
    const int r = tid >> 4, q16 = tid & 15;
    float z[4];
#pragma unroll
    for (int jj = 0; jj < 4; ++jj) z[jj] = __shfl(zval, (lane & ~15) + jj);
#pragma unroll
    for (int u = 0; u < 7; ++u) {
      const int c4 = u * 16 + q16;               // 104 groups of 4 cols
      if (c4 < 104) {
        ushort4 hh;
        u16* hw = (u16*)&hh;
        if (c4 < 100) {                          // cols < 400
          const float4 w0 = *(const float4*)(Wd1 + 0 * HREAL + c4 * 4);
          const float4 w1 = *(const float4*)(Wd1 + 1 * HREAL + c4 * 4);
          const float4 w2 = *(const float4*)(Wd1 + 2 * HREAL + c4 * 4);
          const float4 w3 = *(const float4*)(Wd1 + 3 * HREAL + c4 * 4);
          const float4 bb = *(const float4*)(bd1 + c4 * 4);
          const float ww[4][4] = {{w0.x, w1.x, w2.x, w3.x}, {w0.y, w1.y, w2.y, w3.y},
                                  {w0.z, w1.z, w2.z, w3.z}, {w0.w, w1.w, w2.w, w3.w}};
          const float bbv[4] = {bb.x, bb.y, bb.z, bb.w};
#pragma unroll
          for (int w = 0; w < 4; ++w) {
            float v = fmaf(z[0], ww[w][0], fmaf(z[1], ww[w][1],
                      fmaf(z[2], ww[w][2], fmaf(z[3], ww[w][3], bbv[w]))));
            v = fmaxf(v, 0.1f * v);
            hw[w] = f2bf(v);
          }
        } else {
          hw[0] = hw[1] = hw[2] = hw[3] = 0;
        }
        *(ushort4*)(hp + r * PROW + rotu(r, c4 >> 1) * 16 + (c4 & 1) * 8) = hh;
      }
    }
  }
  __syncthreads();

  // ---- L5: g2 = lrelu(g1 @ Wd2 + bd2) ----
  {
    f32x4 acc[2][4] = {};
    if (wid < 2) gemm_acc<13, 4>(hp, W5, nb0_26, l15, g, acc);
    else         gemm_acc<13, 3>(hp, W5, nb0_26, l15, g, acc);
    __syncthreads();
    if (wid < 2) epi_act<4>(acc, bd2, nb0_26, hp, l15, g);
    else         epi_act<3>(acc, bd2, nb0_26, hp, l15, g);
  }
  __syncthreads();

  // ---- L6: y = tanh(g2 @ Wd3 + bd3) + fused reductions ----
  // 14 n-blocks over 8 waves -> {2,2,2,2,2,2,1,1}
  {
    const int nb0 = (wid < 6) ? wid * 2 : 12 + (wid - 6);
    const int nfw = (wid < 6) ? 2 : 1;
    f32x4 acc[2][4] = {};
    if (wid < 6) gemm_acc<13, 2>(hp, W6, nb0, l15, g, acc);
    else         gemm_acc<13, 1>(hp, W6, nb0, l15, g, acc);
    __syncthreads();               // all plane reads done; red overlays plane
    float* red = (float*)lds;      // [32 rows][8 waves][4]
#pragma unroll
    for (int mf = 0; mf < 2; ++mf) {
#pragma unroll
      for (int j = 0; j < 4; ++j) {
        const int lrow = mf * 16 + g * 4 + j;
        const int grow = row0 + lrow;
        float pA = 0.f, pB = 0.f, pM = 0.f;
#pragma unroll
        for (int nf = 0; nf < 2; ++nf) {
          if (nf < nfw) {
            const int col = (nb0 + nf) * 16 + l15;
            const float v = acc[mf][nf][j] + bd3[col];
            const float e = __expf(2.f * v);
            const float y = 1.f - 2.f * __builtin_amdgcn_rcpf(e + 1.f);
            y_out[(size_t)grow * DDIM + col] = y;
            pA = fmaf(y, dvec[col], pA);
            pB = fmaf(y, y, pB);
            const float df = y - xin[(size_t)grow * DDIM + col];
            pM = fmaf(df, df, pM);
          }
        }
#pragma unroll
        for (int off = 1; off < 16; off <<= 1) {
          pA += __shfl_xor(pA, off);
          pB += __shfl_xor(pB, off);
          pM += __shfl_xor(pM, off);
        }
        if (l15 == 0) {
          red[(lrow * 8 + wid) * 4 + 0] = pA;
          red[(lrow * 8 + wid) * 4 + 1] = pB;
          red[(lrow * 8 + wid) * 4 + 2] = pM;
        }
      }
    }
  }
  __syncthreads();

  if (tid < 32) {
    const float Cn = Cptr[0];
    const float* red = (const float*)lds;
    float A = 0.f, B2 = 0.f, M = 0.f;
#pragma unroll
    for (int w = 0; w < 8; ++w) {
      A  += red[(tid * 8 + w) * 4 + 0];
      B2 += red[(tid * 8 + w) * 4 + 1];
      M  += red[(tid * 8 + w) * 4 + 2];
    }
    defen[row0 + tid] = A / (sqrtf(B2) * Cn + 1e-5f);
#pragma unroll
    for (int off = 1; off < 32; off <<= 1) M += __shfl_xor(M, off);
    if (tid == 0) msep[blockIdx.x] = M;
  }
}

// ---------------- top-k stage A: 64 blocks, per-block top-20 of 2048 ----------------
__global__ void k_topk_a(const float* __restrict__ defen, float* __restrict__ cand) {
  __shared__ float vals[2048];
  __shared__ float wv[4];
  __shared__ int wi[4];
  const int tid = threadIdx.x;
  const int base = blockIdx.x * 2048;
  for (int i = tid; i < 2048; i += 256) vals[i] = defen[base + i];
  __syncthreads();
  for (int it = 0; it < 20; ++it) {
    float mv = -1e30f; int mi = 1 << 30;
    for (int i = tid; i < 2048; i += 256) {
      float v = vals[i];
      if (v > mv) { mv = v; mi = i; }
    }
#pragma unroll
    for (int off = 1; off < 64; off <<= 1) {
      float ov = __shfl_xor(mv, off); int oi = __shfl_xor(mi, off);
      if (ov > mv || (ov == mv && oi < mi)) { mv = ov; mi = oi; }
    }
    if ((tid & 63) == 0) { wv[tid >> 6] = mv; wi[tid >> 6] = mi; }
    __syncthreads();
    if (tid == 0) {
      float bv = wv[0]; int bi = wi[0];
      for (int q = 1; q < 4; ++q)
        if (wv[q] > bv || (wv[q] == bv && wi[q] < bi)) { bv = wv[q]; bi = wi[q]; }
      cand[blockIdx.x * 20 + it] = bv;
      vals[bi] = -1e30f;
    }
    __syncthreads();
  }
}

// ---------------- top-k stage B: final top-20 of 1280 + R_loss ----------------
__global__ void k_topk_b(const float* __restrict__ cand, const float* __restrict__ msep,
                         float* __restrict__ rloss) {
  __shared__ float vals[1280];
  __shared__ float wv[4];
  __shared__ int wi[4];
  __shared__ float msum[4];
  const int tid = threadIdx.x;
  for (int i = tid; i < 1280; i += 256) vals[i] = cand[i];
  float ms = 0.f;
  for (int i = tid; i < 4096; i += 256) ms += msep[i];
#pragma unroll
  for (int off = 1; off < 64; off <<= 1) ms += __shfl_xor(ms, off);
  if ((tid & 63) == 0) msum[tid >> 6] = ms;
  __syncthreads();
  float sam = 0.f;
  for (int it = 0; it < 20; ++it) {
    float mv = -1e30f; int mi = 1 << 30;
    for (int i = tid; i < 1280; i += 256) {
      float v = vals[i];
      if (v > mv) { mv = v; mi = i; }
    }
#pragma unroll
    for (int off = 1; off < 64; off <<= 1) {
      float ov = __shfl_xor(mv, off); int oi = __shfl_xor(mi, off);
      if (ov > mv || (ov == mv && oi < mi)) { mv = ov; mi = oi; }
    }
    if ((tid & 63) == 0) { wv[tid >> 6] = mv; wi[tid >> 6] = mi; }
    __syncthreads();
    if (tid == 0) {
      float bv = wv[0]; int bi = wi[0];
      for (int q = 1; q < 4; ++q)
        if (wv[q] > bv || (wv[q] == bv && wi[q] < bi)) { bv = wv[q]; bi = wi[q]; }
      sam += bv;
      vals[bi] = -1e30f;
    }
    __syncthreads();
  }
  if (tid == 0) {
    float mse = (msum[0] + msum[1] + msum[2] + msum[3]) / 29360128.f;  // N*D
    rloss[0] = mse + 0.1f * sam;
  }
}

extern "C" void kernel_launch(void* const* d_in, const int* in_sizes, int n_in,
                              void* d_out, int out_size, void* d_ws, size_t ws_size,
                              hipStream_t stream) {
  const float* x    = (const float*)d_in[0];
  const float* dinp = (const float*)d_in[1];
  const float* We1  = (const float*)d_in[2];
  const float* be1  = (const float*)d_in[3];
  const float* We2  = (const float*)d_in[4];
  const float* be2  = (const float*)d_in[5];
  const float* We3  = (const float*)d_in[6];
  const float* be3  = (const float*)d_in[7];
  const float* Wd1  = (const float*)d_in[8];
  const float* bd1  = (const float*)d_in[9];
  const float* Wd2  = (const float*)d_in[10];
  const float* bd2  = (const float*)d_in[11];
  const float* Wd3  = (const float*)d_in[12];
  const float* bd3  = (const float*)d_in[13];

  float* y_out = (float*)d_out;
  float* z_out = y_out + (size_t)NROWS * DDIM;
  float* r_out = z_out + (size_t)NROWS * 4;

  char* ws = (char*)d_ws;
  u16* W1 = (u16*)(ws + OFF_W1);
  u16* W2 = (u16*)(ws + OFF_W2);
  u16* W5 = (u16*)(ws + OFF_W5);
  u16* W6 = (u16*)(ws + OFF_W6);
  float* Cf    = (float*)(ws + OFF_C);
  float* msep  = (float*)(ws + OFF_MSEP);
  float* defen = (float*)(ws + OFF_DEFEN);
  float* cand  = (float*)(ws + OFF_CAND);
  float* We3T  = (float*)(ws + OFF_WE3T);

  (void)hipFuncSetAttribute((const void*)k_main, hipFuncAttributeMaxDynamicSharedMemorySize, LDS_TOTAL);

  k_prep<<<dim3(256), dim3(256), 0, stream>>>(We1, We2, Wd2, Wd3, We3, dinp,
                                              W1, W2, W5, W6, We3T, Cf);
  k_main<<<dim3(4096), dim3(512), LDS_TOTAL, stream>>>(x, dinp, be1, be2, be3, bd1, bd2, bd3,
                                                       We3T, Wd1, W1, W2, W5, W6,
                                                       Cf, y_out, z_out, defen, msep);
  k_topk_a<<<dim3(64), dim3(256), 0, stream>>>(defen, cand);
  k_topk_b<<<dim3(1), dim3(256), 0, stream>>>(cand, msep, r_out);
}